// Round 1
// baseline (1437.006 us; speedup 1.0000x reference)
//
#include <hip/hip_runtime.h>
#include <math.h>

#define BB  4
#define CC  256
#define DQK 32
#define NN  4096
#define TI  8

// ---------------------------------------------------------------------------
// Kernel A: fused QKV projection.
// q[b,d,n] = Wq[d,:]·x[b,:,n] + bq[d]   (rows 0..31)
// k[b,d,n] = Wk[d,:]·x[b,:,n] + bk[d]   (rows 32..63)
// v[b,o,n] = Wv[o,:]·x[b,:,n] + bv[o]   (rows 64..319)
// grid (NN/256, 320, BB), block 256
// ---------------------------------------------------------------------------
__global__ __launch_bounds__(256) void qkv_kernel(
    const float* __restrict__ x,
    const float* __restrict__ Wq, const float* __restrict__ bq,
    const float* __restrict__ Wk, const float* __restrict__ bk,
    const float* __restrict__ Wv, const float* __restrict__ bv,
    float* __restrict__ q, float* __restrict__ k, float* __restrict__ v)
{
    const int t = threadIdx.x;
    const int n = blockIdx.x * 256 + t;
    const int r = blockIdx.y;
    const int b = blockIdx.z;

    __shared__ float w_s[CC];

    const float* wrow;
    float bias;
    float* outp;
    if (r < DQK) {
        wrow = Wq + r * CC;            bias = bq[r];
        outp = q + ((size_t)b * DQK + r) * NN;
    } else if (r < 2 * DQK) {
        const int rr = r - DQK;
        wrow = Wk + rr * CC;           bias = bk[rr];
        outp = k + ((size_t)b * DQK + rr) * NN;
    } else {
        const int rr = r - 2 * DQK;
        wrow = Wv + rr * CC;           bias = bv[rr];
        outp = v + ((size_t)b * CC + rr) * NN;
    }

    w_s[t] = wrow[t];           // blockDim == CC == 256
    __syncthreads();

    const float* xb = x + (size_t)b * CC * NN + n;
    float acc = bias;
    #pragma unroll 8
    for (int c = 0; c < CC; ++c)
        acc = fmaf(w_s[c], xb[(size_t)c * NN], acc);
    outp[n] = acc;
}

// ---------------------------------------------------------------------------
// Kernel B: flash-style attention + PV + residual.
// One block handles (batch b, TI=8 consecutive query rows i0..i0+7).
// 256 threads; thread t owns output channel c=t; acc[TI] in registers.
// Online softmax: wave w reduces rows {w, w+4} via shfl butterfly.
// grid (NN/TI, BB), block 256
// ---------------------------------------------------------------------------
__global__ __launch_bounds__(256) void attn_kernel(
    const float* __restrict__ q, const float* __restrict__ k,
    const float* __restrict__ v, const float* __restrict__ x,
    const float* __restrict__ gamma_p, float* __restrict__ out)
{
    const int b    = blockIdx.y;
    const int i0   = blockIdx.x * TI;
    const int t    = threadIdx.x;
    const int wave = t >> 6;
    const int lane = t & 63;

    __shared__ float q_s[TI][DQK];       // 1 KB
    __shared__ float s_s[TI][256];       // 8 KB
    __shared__ float p_s[256][TI];       // 8 KB (transposed for float4 PV reads)
    __shared__ float alpha_s[TI];
    __shared__ float l_s[TI];

    // load the 8 query rows: q_s[r][d] = q[b,d,i0+r]
    {
        const int r = t / DQK, d = t % DQK;   // t covers TI*DQK == 256 exactly
        q_s[r][d] = q[((size_t)b * DQK + d) * NN + i0 + r];
    }
    __syncthreads();

    float m0 = -INFINITY, m1 = -INFINITY;   // running max, rows wave & wave+4
    float l0 = 0.f, l1 = 0.f;               // running denom
    float acc[TI];
    #pragma unroll
    for (int r = 0; r < TI; ++r) acc[r] = 0.f;

    const float scale = 0.17677669529663687f;  // 1/sqrt(32)
    const float* kb = k + (size_t)b * DQK * NN;
    const float* vb = v + (size_t)b * CC * NN + (size_t)t * NN;

    for (int j0 = 0; j0 < NN; j0 += 256) {
        // ---- 1. scores: thread t loads k column j0+t, dots with 8 q rows
        float kr[DQK];
        #pragma unroll
        for (int d = 0; d < DQK; ++d)
            kr[d] = kb[(size_t)d * NN + j0 + t];
        #pragma unroll
        for (int r = 0; r < TI; ++r) {
            float s = 0.f;
            #pragma unroll
            for (int d = 0; d < DQK; ++d)
                s = fmaf(q_s[r][d], kr[d], s);
            s_s[r][t] = s * scale;
        }
        __syncthreads();

        // ---- 2. online softmax: wave w handles rows w and w+4
        #pragma unroll
        for (int rr = 0; rr < 2; ++rr) {
            const int r = wave + rr * 4;
            float v0 = s_s[r][lane], v1 = s_s[r][lane + 64];
            float v2 = s_s[r][lane + 128], v3 = s_s[r][lane + 192];
            float tmax = fmaxf(fmaxf(v0, v1), fmaxf(v2, v3));
            #pragma unroll
            for (int off = 32; off; off >>= 1)
                tmax = fmaxf(tmax, __shfl_xor(tmax, off));
            const float mrun = rr ? m1 : m0;
            const float lrun = rr ? l1 : l0;
            const float mnew = fmaxf(mrun, tmax);
            const float alpha = __expf(mrun - mnew);   // first tile: exp(-inf)=0
            const float p0 = __expf(v0 - mnew), p1 = __expf(v1 - mnew);
            const float p2 = __expf(v2 - mnew), p3 = __expf(v3 - mnew);
            p_s[lane][r] = p0;       p_s[lane + 64][r] = p1;
            p_s[lane + 128][r] = p2; p_s[lane + 192][r] = p3;
            float psum = p0 + p1 + p2 + p3;
            #pragma unroll
            for (int off = 32; off; off >>= 1)
                psum += __shfl_xor(psum, off);
            const float lnew = lrun * alpha + psum;
            if (rr) { m1 = mnew; l1 = lnew; } else { m0 = mnew; l0 = lnew; }
            if (lane == 0) alpha_s[r] = alpha;
        }
        __syncthreads();

        // ---- 3. rescale + PV: acc[r] = acc[r]*alpha[r] + sum_j p[r][j]*v[c][j]
        #pragma unroll
        for (int r = 0; r < TI; ++r) acc[r] *= alpha_s[r];
        for (int j = 0; j < 256; ++j) {
            const float vv = vb[j0 + j];
            const float4 pa = *(const float4*)&p_s[j][0];
            const float4 pb = *(const float4*)&p_s[j][4];
            acc[0] = fmaf(pa.x, vv, acc[0]);
            acc[1] = fmaf(pa.y, vv, acc[1]);
            acc[2] = fmaf(pa.z, vv, acc[2]);
            acc[3] = fmaf(pa.w, vv, acc[3]);
            acc[4] = fmaf(pb.x, vv, acc[4]);
            acc[5] = fmaf(pb.y, vv, acc[5]);
            acc[6] = fmaf(pb.z, vv, acc[6]);
            acc[7] = fmaf(pb.w, vv, acc[7]);
        }
        __syncthreads();   // protect s_s/p_s before next tile
    }

    if (lane == 0) { l_s[wave] = l0; l_s[wave + 4] = l1; }
    __syncthreads();

    const float g = gamma_p[0];
    const float* xb = x + (size_t)b * CC * NN + (size_t)t * NN;
    float* ob = out + (size_t)b * CC * NN + (size_t)t * NN;
    #pragma unroll
    for (int r = 0; r < TI; ++r)
        ob[i0 + r] = g * (acc[r] / l_s[r]) + xb[i0 + r];
}

// ---------------------------------------------------------------------------
extern "C" void kernel_launch(void* const* d_in, const int* in_sizes, int n_in,
                              void* d_out, int out_size, void* d_ws, size_t ws_size,
                              hipStream_t stream)
{
    const float* x     = (const float*)d_in[0];
    const float* Wq    = (const float*)d_in[1];
    const float* bq    = (const float*)d_in[2];
    const float* Wk    = (const float*)d_in[3];
    const float* bk    = (const float*)d_in[4];
    const float* Wv    = (const float*)d_in[5];
    const float* bv    = (const float*)d_in[6];
    const float* gamma = (const float*)d_in[7];
    float* out = (float*)d_out;

    // workspace: q (2 MB) | k (2 MB) | v (16 MB)
    float* q = (float*)d_ws;
    float* k = q + (size_t)BB * DQK * NN;
    float* v = k + (size_t)BB * DQK * NN;

    dim3 gridA(NN / 256, 2 * DQK + CC, BB);
    qkv_kernel<<<gridA, 256, 0, stream>>>(x, Wq, bq, Wk, bk, Wv, bv, q, k, v);

    dim3 gridB(NN / TI, BB);
    attn_kernel<<<gridB, 256, 0, stream>>>(q, k, v, x, gamma, out);
}

// Round 2
// 241.306 us; speedup vs baseline: 5.9551x; 5.9551x over previous
//
#include <hip/hip_runtime.h>
#include <hip/hip_bf16.h>
#include <math.h>

#define BB   4
#define CC   256
#define DQK  32
#define NN   4096
#define QBLK 64
#define KVB  128
#define NTILES (NN / KVB)
#define SCALE 0.17677669529663687f   // 1/sqrt(32 + 1e-8)

typedef short  bf16x8 __attribute__((ext_vector_type(8)));
typedef float  f32x4  __attribute__((ext_vector_type(4)));
typedef unsigned short u16;

__device__ __forceinline__ u16 f2bf(float f) {
    __hip_bfloat16 h = __float2bfloat16(f);   // round-to-nearest
    return *reinterpret_cast<u16*>(&h);
}

// ---------------------------------------------------------------------------
// Kernel A: QKV projection -> bf16, MFMA-friendly layouts.
//   Qt[b][n][32] (scale folded in), Kt[b][n][32], V[b][c][n]
// grid (NN/256, 320/8, BB), block 256. Weight reads are block-uniform
// (scalarize to s_load); x reads coalesced.
// ---------------------------------------------------------------------------
__global__ __launch_bounds__(256) void qkv_kernel(
    const float* __restrict__ x,
    const float* __restrict__ Wq, const float* __restrict__ bq,
    const float* __restrict__ Wk, const float* __restrict__ bk,
    const float* __restrict__ Wv, const float* __restrict__ bv,
    u16* __restrict__ qt, u16* __restrict__ kt, u16* __restrict__ v)
{
    const int t  = threadIdx.x;
    const int n  = blockIdx.x * 256 + t;
    const int r0 = blockIdx.y * 8;          // first of 8 output rows
    const int b  = blockIdx.z;

    const float* wbase;
    const float* bias;
    if (r0 < DQK)          { wbase = Wq + r0 * CC;            bias = bq + r0; }
    else if (r0 < 2 * DQK) { wbase = Wk + (r0 - DQK) * CC;    bias = bk + (r0 - DQK); }
    else                   { wbase = Wv + (r0 - 2 * DQK) * CC; bias = bv + (r0 - 2 * DQK); }

    float acc[8];
    #pragma unroll
    for (int i = 0; i < 8; ++i) acc[i] = bias[i];

    const float* xb = x + (size_t)b * CC * NN + n;
    #pragma unroll 4
    for (int c = 0; c < CC; ++c) {
        const float xv = xb[(size_t)c * NN];
        #pragma unroll
        for (int i = 0; i < 8; ++i)
            acc[i] = fmaf(wbase[i * CC + c], xv, acc[i]);
    }

    if (r0 < DQK) {
        u16* o = qt + ((size_t)b * NN + n) * DQK + r0;
        #pragma unroll
        for (int i = 0; i < 8; ++i) o[i] = f2bf(acc[i] * SCALE);
    } else if (r0 < 2 * DQK) {
        u16* o = kt + ((size_t)b * NN + n) * DQK + (r0 - DQK);
        #pragma unroll
        for (int i = 0; i < 8; ++i) o[i] = f2bf(acc[i]);
    } else {
        #pragma unroll
        for (int i = 0; i < 8; ++i)
            v[((size_t)b * CC + (r0 - 2 * DQK + i)) * NN + n] = f2bf(acc[i]);
    }
}

// ---------------------------------------------------------------------------
// Kernel B: MFMA flash attention.
// Block = 256 thr (4 waves), QBLK=64 q-rows, KVB=128 kv-cols per tile.
// Wave w: QK^T + softmax for q rows [i0+16w, +16); PV computes
// O^T[c in w*64..+64][all 64 q].  P goes through XOR-swizzled LDS (bf16).
// grid 256 (1D, XCD-swizzled: batch b -> XCDs 2b,2b+1), block 256.
// ---------------------------------------------------------------------------
__global__ __launch_bounds__(256) void attn_kernel(
    const u16* __restrict__ qt, const u16* __restrict__ kt,
    const u16* __restrict__ vg, const float* __restrict__ x,
    const float* __restrict__ gamma_p, float* __restrict__ out)
{
    const int id   = blockIdx.x;
    const int xcd  = id & 7;
    const int b    = xcd >> 1;
    const int i0   = (((xcd & 1) << 5) + (id >> 3)) * QBLK;
    const int t    = threadIdx.x;
    const int wid  = t >> 6;
    const int lane = t & 63;
    const int g    = lane >> 4;     // quarter-wave group
    const int c16  = lane & 15;

    __shared__ u16   P_s[QBLK * KVB];   // 16 KB, XOR-swizzled
    __shared__ float alpha_s[QBLK];
    __shared__ float l_s[QBLK];

    // Q A-fragment, resident all loop: lane holds Q[q=i0+16w+c16][d=8g..8g+7]
    const bf16x8 qa = *(const bf16x8*)(qt + ((size_t)b * NN + i0 + wid * 16 + c16) * DQK + g * 8);

    float m[4], l[4];
    #pragma unroll
    for (int r = 0; r < 4; ++r) { m[r] = -INFINITY; l[r] = 0.f; }

    f32x4 accv[4][4];
    #pragma unroll
    for (int cf = 0; cf < 4; ++cf)
        #pragma unroll
        for (int qf = 0; qf < 4; ++qf)
            #pragma unroll
            for (int r = 0; r < 4; ++r) accv[cf][qf][r] = 0.f;

    const u16* ktb = kt + (size_t)b * NN * DQK;
    const u16* vb  = vg + (size_t)b * CC * NN;

    for (int jt = 0; jt < NTILES; ++jt) {
        const int j0 = jt * KVB;

        // ---- S = Q K^T  (per wave: 16 q x 128 j), scale pre-folded into Q
        f32x4 s[8];
        #pragma unroll
        for (int jf = 0; jf < 8; ++jf) {
            const bf16x8 kb = *(const bf16x8*)(ktb + (size_t)(j0 + jf * 16 + c16) * DQK + g * 8);
            s[jf] = __builtin_amdgcn_mfma_f32_16x16x32_bf16(qa, kb, (f32x4){0.f, 0.f, 0.f, 0.f}, 0, 0, 0);
        }

        // ---- online softmax (rows r: q = i0+16w+4g+r), reduce over 16 lanes
        float alpha[4];
        #pragma unroll
        for (int r = 0; r < 4; ++r) {
            float tm = s[0][r];
            #pragma unroll
            for (int jf = 1; jf < 8; ++jf) tm = fmaxf(tm, s[jf][r]);
            #pragma unroll
            for (int off = 8; off; off >>= 1) tm = fmaxf(tm, __shfl_xor(tm, off));
            const float mn = fmaxf(m[r], tm);
            alpha[r] = __expf(m[r] - mn);
            float ls = 0.f;
            #pragma unroll
            for (int jf = 0; jf < 8; ++jf) {
                const float p = __expf(s[jf][r] - mn);
                s[jf][r] = p;
                ls += p;
            }
            #pragma unroll
            for (int off = 8; off; off >>= 1) ls += __shfl_xor(ls, off);
            l[r] = l[r] * alpha[r] + ls;
            m[r] = mn;
        }

        const int qbase = wid * 16 + g * 4;
        if (c16 == 0) {
            #pragma unroll
            for (int r = 0; r < 4; ++r) alpha_s[qbase + r] = alpha[r];
        }
        // P -> LDS bf16, swizzle: ushort index ^= (row&15)<<3 (byte ^=(row&15)<<4)
        #pragma unroll
        for (int r = 0; r < 4; ++r) {
            const int row = qbase + r;
            const int swz = (row & 15) << 3;
            #pragma unroll
            for (int jf = 0; jf < 8; ++jf)
                P_s[(row * KVB + c16 + jf * 16) ^ swz] = f2bf(s[jf][r]);
        }
        __syncthreads();

        // ---- rescale accumulators by alpha of their q-column
        float av[4];
        #pragma unroll
        for (int qf = 0; qf < 4; ++qf) av[qf] = alpha_s[c16 + 16 * qf];
        #pragma unroll
        for (int cf = 0; cf < 4; ++cf)
            #pragma unroll
            for (int qf = 0; qf < 4; ++qf)
                #pragma unroll
                for (int r = 0; r < 4; ++r) accv[cf][qf][r] *= av[qf];

        // ---- PV: O^T[c][q] += V[c][j] * P[q][j]
        #pragma unroll
        for (int ks = 0; ks < 4; ++ks) {
            bf16x8 pb[4];
            #pragma unroll
            for (int qf = 0; qf < 4; ++qf) {
                const int row = c16 + 16 * qf;
                const int e   = (row * KVB + ks * 32 + g * 8) ^ ((row & 15) << 3);
                pb[qf] = *(const bf16x8*)&P_s[e];
            }
            #pragma unroll
            for (int cf = 0; cf < 4; ++cf) {
                const bf16x8 va = *(const bf16x8*)(vb + (size_t)(wid * 64 + cf * 16 + c16) * NN + j0 + ks * 32 + g * 8);
                #pragma unroll
                for (int qf = 0; qf < 4; ++qf)
                    accv[cf][qf] = __builtin_amdgcn_mfma_f32_16x16x32_bf16(va, pb[qf], accv[cf][qf], 0, 0, 0);
            }
        }
        __syncthreads();
    }

    // ---- epilogue: out = gamma * O/l + x
    if (c16 == 0) {
        #pragma unroll
        for (int r = 0; r < 4; ++r) l_s[wid * 16 + g * 4 + r] = l[r];
    }
    __syncthreads();

    const float gam = gamma_p[0];
    #pragma unroll
    for (int qf = 0; qf < 4; ++qf) {
        const float linv = 1.0f / l_s[c16 + 16 * qf];
        const int   qcol = i0 + c16 + 16 * qf;
        #pragma unroll
        for (int cf = 0; cf < 4; ++cf) {
            #pragma unroll
            for (int r = 0; r < 4; ++r) {
                const int    c = wid * 64 + cf * 16 + g * 4 + r;
                const size_t o = ((size_t)b * CC + c) * NN + qcol;
                out[o] = gam * (accv[cf][qf][r] * linv) + x[o];
            }
        }
    }
}

// ---------------------------------------------------------------------------
extern "C" void kernel_launch(void* const* d_in, const int* in_sizes, int n_in,
                              void* d_out, int out_size, void* d_ws, size_t ws_size,
                              hipStream_t stream)
{
    const float* x     = (const float*)d_in[0];
    const float* Wq    = (const float*)d_in[1];
    const float* bq    = (const float*)d_in[2];
    const float* Wk    = (const float*)d_in[3];
    const float* bk    = (const float*)d_in[4];
    const float* Wv    = (const float*)d_in[5];
    const float* bv    = (const float*)d_in[6];
    const float* gamma = (const float*)d_in[7];
    float* out = (float*)d_out;

    // workspace (bf16): Qt 1MB | Kt 1MB | V 8MB
    u16* qt = (u16*)d_ws;
    u16* kt = qt + (size_t)BB * NN * DQK;
    u16* v  = kt + (size_t)BB * NN * DQK;

    dim3 gridA(NN / 256, (2 * DQK + CC) / 8, BB);
    qkv_kernel<<<gridA, 256, 0, stream>>>(x, Wq, bq, Wk, bk, Wv, bv, qt, kt, v);

    attn_kernel<<<dim3(BB * (NN / QBLK)), 256, 0, stream>>>(qt, kt, v, x, gamma, out);
}

// Round 3
// 160.167 us; speedup vs baseline: 8.9719x; 1.5066x over previous
//
#include <hip/hip_runtime.h>
#include <hip/hip_bf16.h>
#include <math.h>

#define BB   4
#define CC   256
#define DQK  32
#define NN   4096
#define QBLK 64
#define KVB  128
#define NTILES (NN / KVB)
#define SCALE 0.17677669529663687f   // 1/sqrt(32 + 1e-8)

typedef short  bf16x8 __attribute__((ext_vector_type(8)));
typedef float  f32x4  __attribute__((ext_vector_type(4)));
typedef unsigned short u16;

__device__ __forceinline__ u16 f2bf(float f) {
    __hip_bfloat16 h = __float2bfloat16(f);   // round-to-nearest
    return *reinterpret_cast<u16*>(&h);
}

// ---------------------------------------------------------------------------
// Kernel A: QKV projection -> bf16, MFMA-friendly layouts.
//   Qt[b][n][32] (scale folded in), Kt[b][n][32], V[b][c][n]
// 16 output rows per block. grid (NN/256, 320/16, BB), block 256.
// W reads are wave-uniform -> s_load; x reads coalesced.
// ---------------------------------------------------------------------------
__global__ __launch_bounds__(256) void qkv_kernel(
    const float* __restrict__ x,
    const float* __restrict__ Wq, const float* __restrict__ bq,
    const float* __restrict__ Wk, const float* __restrict__ bk,
    const float* __restrict__ Wv, const float* __restrict__ bv,
    u16* __restrict__ qt, u16* __restrict__ kt, u16* __restrict__ v)
{
    const int t  = threadIdx.x;
    const int n  = blockIdx.x * 256 + t;
    const int r0 = blockIdx.y * 16;         // first of 16 output rows
    const int b  = blockIdx.z;

    const float* wbase;
    const float* bias;
    if (r0 < DQK)          { wbase = Wq + r0 * CC;             bias = bq + r0; }
    else if (r0 < 2 * DQK) { wbase = Wk + (r0 - DQK) * CC;     bias = bk + (r0 - DQK); }
    else                   { wbase = Wv + (r0 - 2 * DQK) * CC; bias = bv + (r0 - 2 * DQK); }

    float acc[16];
    #pragma unroll
    for (int i = 0; i < 16; ++i) acc[i] = bias[i];

    const float* xb = x + (size_t)b * CC * NN + n;
    #pragma unroll 2
    for (int c = 0; c < CC; ++c) {
        const float xv = xb[(size_t)c * NN];
        #pragma unroll
        for (int i = 0; i < 16; ++i)
            acc[i] = fmaf(wbase[i * CC + c], xv, acc[i]);
    }

    if (r0 < DQK) {
        u16* o = qt + ((size_t)b * NN + n) * DQK + r0;
        #pragma unroll
        for (int i = 0; i < 16; ++i) o[i] = f2bf(acc[i] * SCALE);
    } else if (r0 < 2 * DQK) {
        u16* o = kt + ((size_t)b * NN + n) * DQK + (r0 - DQK);
        #pragma unroll
        for (int i = 0; i < 16; ++i) o[i] = f2bf(acc[i]);
    } else {
        #pragma unroll
        for (int i = 0; i < 16; ++i)
            v[((size_t)b * CC + (r0 - 2 * DQK + i)) * NN + n] = f2bf(acc[i]);
    }
}

// ---------------------------------------------------------------------------
// Kernel B: MFMA flash attention, 8 waves (512 thr), pipelined.
// Waves 0-3: QK^T + softmax for q rows [i0+16w, +16), write P -> P_s[t&1].
// All 8 waves: PV, channel split 8x (wave w owns channels 32w..32w+31).
// One barrier per tile; P/alpha double-buffered so PV(t) overlaps QK(t+1).
// V frags prefetched at loop top; K tile t+1 prefetched under softmax.
// grid 256 (XCD-swizzled), block 512.
// ---------------------------------------------------------------------------
__global__ __launch_bounds__(512, 2) void attn_kernel(
    const u16* __restrict__ qt, const u16* __restrict__ kt,
    const u16* __restrict__ vg, const float* __restrict__ x,
    const float* __restrict__ gamma_p, float* __restrict__ out)
{
    const int id   = blockIdx.x;
    const int xcd  = id & 7;
    const int b    = xcd >> 1;
    const int i0   = (((xcd & 1) << 5) + (id >> 3)) * QBLK;
    const int t    = threadIdx.x;
    const int wid  = t >> 6;        // 0..7
    const int lane = t & 63;
    const int g    = lane >> 4;
    const int c16  = lane & 15;

    __shared__ u16   P_s[2][QBLK * KVB];    // 2 x 16 KB, XOR-swizzled
    __shared__ float alpha_s[2][QBLK];
    __shared__ float l_s[QBLK];

    const bool qkw = (wid < 4);

    // Q A-fragment (QK waves): lane holds Q[q=i0+16w+c16][d=8g..8g+7]
    const bf16x8 qa = *(const bf16x8*)(qt + ((size_t)b * NN + i0 + (wid & 3) * 16 + c16) * DQK + g * 8);

    float m[4], l[4];
    #pragma unroll
    for (int r = 0; r < 4; ++r) { m[r] = -INFINITY; l[r] = 0.f; }

    f32x4 accv[2][4];   // [cf][qf]
    #pragma unroll
    for (int cf = 0; cf < 2; ++cf)
        #pragma unroll
        for (int qf = 0; qf < 4; ++qf)
            #pragma unroll
            for (int r = 0; r < 4; ++r) accv[cf][qf][r] = 0.f;

    const u16* ktb = kt + (size_t)b * NN * DQK;
    const u16* vb  = vg + (size_t)b * CC * NN + (size_t)(wid * 32) * NN;

    // preload K tile 0
    bf16x8 kb[8];
    if (qkw) {
        #pragma unroll
        for (int jf = 0; jf < 8; ++jf)
            kb[jf] = *(const bf16x8*)(ktb + (size_t)(jf * 16 + c16) * DQK + g * 8);
    }

    for (int jt = 0; jt < NTILES; ++jt) {
        const int j0  = jt * KVB;
        const int buf = jt & 1;

        // ---- V prefetch for this tile (all waves): lands under QK/softmax
        bf16x8 va[2][4];
        #pragma unroll
        for (int cf = 0; cf < 2; ++cf)
            #pragma unroll
            for (int ks = 0; ks < 4; ++ks)
                va[cf][ks] = *(const bf16x8*)(vb + (size_t)(cf * 16 + c16) * NN + j0 + ks * 32 + g * 8);

        if (qkw) {
            // ---- S = Q K^T (16 q x 128 j)
            f32x4 s[8];
            #pragma unroll
            for (int jf = 0; jf < 8; ++jf)
                s[jf] = __builtin_amdgcn_mfma_f32_16x16x32_bf16(qa, kb[jf], (f32x4){0.f, 0.f, 0.f, 0.f}, 0, 0, 0);

            // ---- prefetch next K tile (lands under softmax + PV)
            const int jn = ((jt + 1) & (NTILES - 1)) * KVB;
            #pragma unroll
            for (int jf = 0; jf < 8; ++jf)
                kb[jf] = *(const bf16x8*)(ktb + (size_t)(jn + jf * 16 + c16) * DQK + g * 8);

            // ---- online softmax (rows r: q-local = 16w + 4g + r)
            float alpha[4];
            #pragma unroll
            for (int r = 0; r < 4; ++r) {
                float tm = s[0][r];
                #pragma unroll
                for (int jf = 1; jf < 8; ++jf) tm = fmaxf(tm, s[jf][r]);
                #pragma unroll
                for (int off = 8; off; off >>= 1) tm = fmaxf(tm, __shfl_xor(tm, off));
                const float mn = fmaxf(m[r], tm);
                alpha[r] = __expf(m[r] - mn);
                float ls = 0.f;
                #pragma unroll
                for (int jf = 0; jf < 8; ++jf) {
                    const float p = __expf(s[jf][r] - mn);
                    s[jf][r] = p;
                    ls += p;
                }
                #pragma unroll
                for (int off = 8; off; off >>= 1) ls += __shfl_xor(ls, off);
                l[r] = l[r] * alpha[r] + ls;
                m[r] = mn;
            }

            const int qbase = (wid & 3) * 16 + g * 4;
            if (c16 == 0) {
                #pragma unroll
                for (int r = 0; r < 4; ++r) alpha_s[buf][qbase + r] = alpha[r];
            }
            // P -> LDS bf16, swizzle: ushort idx ^= (row&15)<<3
            #pragma unroll
            for (int r = 0; r < 4; ++r) {
                const int row = qbase + r;
                const int swz = (row & 15) << 3;
                #pragma unroll
                for (int jf = 0; jf < 8; ++jf)
                    P_s[buf][(row * KVB + c16 + jf * 16) ^ swz] = f2bf(s[jf][r]);
            }
        }
        __syncthreads();   // P_s[buf]/alpha_s[buf] ready; also fences prev PV reads

        // ---- rescale accumulators by alpha of their q-column
        float av[4];
        #pragma unroll
        for (int qf = 0; qf < 4; ++qf) av[qf] = alpha_s[buf][c16 + 16 * qf];
        #pragma unroll
        for (int cf = 0; cf < 2; ++cf)
            #pragma unroll
            for (int qf = 0; qf < 4; ++qf)
                #pragma unroll
                for (int r = 0; r < 4; ++r) accv[cf][qf][r] *= av[qf];

        // ---- PV: O^T[c][q] += V[c][j] * P[q][j]
        #pragma unroll
        for (int ks = 0; ks < 4; ++ks) {
            bf16x8 pb[4];
            #pragma unroll
            for (int qf = 0; qf < 4; ++qf) {
                const int row = c16 + 16 * qf;
                const int e   = (row * KVB + ks * 32 + g * 8) ^ ((row & 15) << 3);
                pb[qf] = *(const bf16x8*)&P_s[buf][e];
            }
            #pragma unroll
            for (int cf = 0; cf < 2; ++cf) {
                #pragma unroll
                for (int qf = 0; qf < 4; ++qf)
                    accv[cf][qf] = __builtin_amdgcn_mfma_f32_16x16x32_bf16(va[cf][ks], pb[qf], accv[cf][qf], 0, 0, 0);
            }
        }
    }

    // ---- epilogue: out = gamma * O/l + x
    if (qkw && c16 == 0) {
        #pragma unroll
        for (int r = 0; r < 4; ++r) l_s[(wid & 3) * 16 + g * 4 + r] = l[r];
    }
    __syncthreads();

    const float gam = gamma_p[0];
    #pragma unroll
    for (int qf = 0; qf < 4; ++qf) {
        const float linv = 1.0f / l_s[c16 + 16 * qf];
        const int   qcol = i0 + c16 + 16 * qf;
        #pragma unroll
        for (int cf = 0; cf < 2; ++cf) {
            #pragma unroll
            for (int r = 0; r < 4; ++r) {
                const int    c = wid * 32 + cf * 16 + g * 4 + r;
                const size_t o = ((size_t)b * CC + c) * NN + qcol;
                out[o] = gam * (accv[cf][qf][r] * linv) + x[o];
            }
        }
    }
}

// ---------------------------------------------------------------------------
extern "C" void kernel_launch(void* const* d_in, const int* in_sizes, int n_in,
                              void* d_out, int out_size, void* d_ws, size_t ws_size,
                              hipStream_t stream)
{
    const float* x     = (const float*)d_in[0];
    const float* Wq    = (const float*)d_in[1];
    const float* bq    = (const float*)d_in[2];
    const float* Wk    = (const float*)d_in[3];
    const float* bk    = (const float*)d_in[4];
    const float* Wv    = (const float*)d_in[5];
    const float* bv    = (const float*)d_in[6];
    const float* gamma = (const float*)d_in[7];
    float* out = (float*)d_out;

    // workspace (bf16): Qt 1MB | Kt 1MB | V 8MB
    u16* qt = (u16*)d_ws;
    u16* kt = qt + (size_t)BB * NN * DQK;
    u16* v  = kt + (size_t)BB * NN * DQK;

    dim3 gridA(NN / 256, (2 * DQK + CC) / 16, BB);
    qkv_kernel<<<gridA, 256, 0, stream>>>(x, Wq, bq, Wk, bk, Wv, bv, qt, kt, v);

    attn_kernel<<<dim3(BB * (NN / QBLK)), 512, 0, stream>>>(qt, kt, v, x, gamma, out);
}

// Round 4
// 133.446 us; speedup vs baseline: 10.7685x; 1.2002x over previous
//
#include <hip/hip_runtime.h>
#include <hip/hip_bf16.h>
#include <math.h>

#define BB   4
#define CC   256
#define DQK  32
#define NN   4096
#define QBLK 64
#define KVB  128
#define NTILES (NN / KVB)
#define SCALE 0.17677669529663687f   // 1/sqrt(32 + 1e-8)

typedef short  bf16x8 __attribute__((ext_vector_type(8)));
typedef float  f32x4  __attribute__((ext_vector_type(4)));
typedef unsigned short u16;

__device__ __forceinline__ u16 f2bf(float f) {
    __hip_bfloat16 h = __float2bfloat16(f);   // round-to-nearest
    return *reinterpret_cast<u16*>(&h);
}

// ---------------------------------------------------------------------------
// Kernel 0: pack W -> bf16 [320][256] (Q rows & bias scaled), bias -> f32[320]
// grid 320, block 256
// ---------------------------------------------------------------------------
__global__ __launch_bounds__(256) void wprep_kernel(
    const float* __restrict__ Wq, const float* __restrict__ bq,
    const float* __restrict__ Wk, const float* __restrict__ bk,
    const float* __restrict__ Wv, const float* __restrict__ bv,
    u16* __restrict__ Wb, float* __restrict__ biasb)
{
    const int r = blockIdx.x;
    const int t = threadIdx.x;
    float w, bias;
    if (r < DQK)          { w = Wq[r * CC + t] * SCALE;             bias = bq[r] * SCALE; }
    else if (r < 2 * DQK) { w = Wk[(r - DQK) * CC + t];             bias = bk[r - DQK];  }
    else                  { w = Wv[(r - 2 * DQK) * CC + t];         bias = bv[r - 2 * DQK]; }
    Wb[r * CC + t] = f2bf(w);
    if (t == 0) biasb[r] = bias;
}

// ---------------------------------------------------------------------------
// Kernel 1: transpose x [B][C][N] f32 -> xbf [B][N][C] bf16.
// 64x64 tiles via LDS. grid (N/64, C/64, B), block 256.
// ---------------------------------------------------------------------------
__global__ __launch_bounds__(256) void xpose_kernel(
    const float* __restrict__ x, u16* __restrict__ xbf)
{
    __shared__ u16 tile[64][65];
    const int b  = blockIdx.z;
    const int n0 = blockIdx.x * 64;
    const int c0 = blockIdx.y * 64;
    const int t  = threadIdx.x;
    const int tl = t & 63;
    const int th = t >> 6;

    #pragma unroll
    for (int rr = 0; rr < 16; ++rr) {
        const int c = th + rr * 4;
        tile[c][tl] = f2bf(x[((size_t)b * CC + c0 + c) * NN + n0 + tl]);
    }
    __syncthreads();
    #pragma unroll
    for (int rr = 0; rr < 16; ++rr) {
        const int n = th + rr * 4;
        xbf[((size_t)b * NN + n0 + n) * CC + c0 + tl] = tile[tl][n];
    }
}

// ---------------------------------------------------------------------------
// Kernel 2: QKV projection as MFMA GEMM: [320 x 256] @ [256 x N].
// Outputs: Qt[b][n][32] (scale folded), Kt[b][n][32], V[b][c][n], all bf16.
// grid (N/64, B) = 256 blocks, block 512 (8 waves: mw=wid&3 over M, nw=wid>>2 over N)
// ---------------------------------------------------------------------------
__global__ __launch_bounds__(512) void qkv_gemm(
    const u16* __restrict__ Wb, const float* __restrict__ biasb,
    const u16* __restrict__ xbf,
    u16* __restrict__ qt, u16* __restrict__ kt, u16* __restrict__ v)
{
    const int b   = blockIdx.y;
    const int n0  = blockIdx.x * 64;
    const int t   = threadIdx.x;
    const int wid = t >> 6;
    const int mw  = wid & 3;        // M group: rows mw*80 .. +80
    const int nw  = wid >> 2;       // N group: cols n0 + nw*32 .. +32
    const int lane = t & 63;
    const int g    = lane >> 4;
    const int c16  = lane & 15;

    f32x4 acc[5][2];
    #pragma unroll
    for (int mf = 0; mf < 5; ++mf)
        #pragma unroll
        for (int nf = 0; nf < 2; ++nf)
            #pragma unroll
            for (int r = 0; r < 4; ++r) acc[mf][nf][r] = 0.f;

    const u16* xb = xbf + (size_t)b * NN * CC;

    #pragma unroll
    for (int kk = 0; kk < 8; ++kk) {
        bf16x8 xf[2];
        #pragma unroll
        for (int nf = 0; nf < 2; ++nf)
            xf[nf] = *(const bf16x8*)(xb + (size_t)(n0 + nw * 32 + nf * 16 + c16) * CC + kk * 32 + g * 8);
        #pragma unroll
        for (int mf = 0; mf < 5; ++mf) {
            const bf16x8 wf = *(const bf16x8*)(Wb + (size_t)(mw * 80 + mf * 16 + c16) * CC + kk * 32 + g * 8);
            #pragma unroll
            for (int nf = 0; nf < 2; ++nf)
                acc[mf][nf] = __builtin_amdgcn_mfma_f32_16x16x32_bf16(wf, xf[nf], acc[mf][nf], 0, 0, 0);
        }
    }

    #pragma unroll
    for (int mf = 0; mf < 5; ++mf) {
        #pragma unroll
        for (int nf = 0; nf < 2; ++nf) {
            const int n = n0 + nw * 32 + nf * 16 + c16;
            #pragma unroll
            for (int r = 0; r < 4; ++r) {
                const int row = mw * 80 + mf * 16 + g * 4 + r;
                const float val = acc[mf][nf][r] + biasb[row];
                if (row < DQK)
                    qt[((size_t)b * NN + n) * DQK + row] = f2bf(val);
                else if (row < 2 * DQK)
                    kt[((size_t)b * NN + n) * DQK + (row - DQK)] = f2bf(val);
                else
                    v[((size_t)b * CC + (row - 2 * DQK)) * NN + n] = f2bf(val);
            }
        }
    }
}

// ---------------------------------------------------------------------------
// Kernel 3: MFMA flash attention, producer/consumer wave split.
// Waves 0-3 (QK): S = Q K^T (16 q-rows each), online softmax, P -> P_s[buf].
// Waves 4-7 (PV): consume P of the PREVIOUS tile (double buffer), 64 ch each.
// One barrier per tile; K prefetched one tile ahead by QK waves.
// grid 256 (XCD-swizzled), block 512.
// ---------------------------------------------------------------------------
__global__ __launch_bounds__(512, 2) void attn_kernel(
    const u16* __restrict__ qt, const u16* __restrict__ kt,
    const u16* __restrict__ vg, const float* __restrict__ x,
    const float* __restrict__ gamma_p, float* __restrict__ out)
{
    const int id   = blockIdx.x;
    const int xcd  = id & 7;
    const int b    = xcd >> 1;
    const int i0   = (((xcd & 1) << 5) + (id >> 3)) * QBLK;
    const int t    = threadIdx.x;
    const int wid  = t >> 6;        // 0..7
    const int lane = t & 63;
    const int g    = lane >> 4;
    const int c16  = lane & 15;

    __shared__ u16   P_s[2][QBLK * KVB];    // 2 x 16 KB, XOR-swizzled
    __shared__ float alpha_s[2][QBLK];
    __shared__ float l_s[QBLK];

    const bool qkw = (wid < 4);
    const u16* ktb = kt + (size_t)b * NN * DQK;
    const u16* vb  = vg + (size_t)b * CC * NN + (size_t)((wid & 3) * 64) * NN;

    // ---- QK-wave state
    bf16x8 qa;
    bf16x8 kb[8];
    float  m[4], l[4];
    // ---- PV-wave state
    f32x4 accv[4][4];   // [cf][qf]: channels (wid-4)*64 + cf*16.., q cols qf*16..

    if (qkw) {
        qa = *(const bf16x8*)(qt + ((size_t)b * NN + i0 + wid * 16 + c16) * DQK + g * 8);
        #pragma unroll
        for (int jf = 0; jf < 8; ++jf)
            kb[jf] = *(const bf16x8*)(ktb + (size_t)(jf * 16 + c16) * DQK + g * 8);
        #pragma unroll
        for (int r = 0; r < 4; ++r) { m[r] = -INFINITY; l[r] = 0.f; }
    } else {
        #pragma unroll
        for (int cf = 0; cf < 4; ++cf)
            #pragma unroll
            for (int qf = 0; qf < 4; ++qf)
                #pragma unroll
                for (int r = 0; r < 4; ++r) accv[cf][qf][r] = 0.f;
    }

    // PV body for tile pj (reads P_s/alpha_s[pbuf])
    auto pv_tile = [&](int pj, int pbuf) {
        const int pj0 = pj * KVB;
        bf16x8 va[4][4];
        #pragma unroll
        for (int cf = 0; cf < 4; ++cf)
            #pragma unroll
            for (int ks = 0; ks < 4; ++ks)
                va[cf][ks] = *(const bf16x8*)(vb + (size_t)(cf * 16 + c16) * NN + pj0 + ks * 32 + g * 8);
        float av[4];
        #pragma unroll
        for (int qf = 0; qf < 4; ++qf) av[qf] = alpha_s[pbuf][c16 + 16 * qf];
        #pragma unroll
        for (int cf = 0; cf < 4; ++cf)
            #pragma unroll
            for (int qf = 0; qf < 4; ++qf)
                #pragma unroll
                for (int r = 0; r < 4; ++r) accv[cf][qf][r] *= av[qf];
        #pragma unroll
        for (int ks = 0; ks < 4; ++ks) {
            bf16x8 pb[4];
            #pragma unroll
            for (int qf = 0; qf < 4; ++qf) {
                const int row = c16 + 16 * qf;
                const int e   = (row * KVB + ks * 32 + g * 8) ^ ((row & 15) << 3);
                pb[qf] = *(const bf16x8*)&P_s[pbuf][e];
            }
            #pragma unroll
            for (int cf = 0; cf < 4; ++cf)
                #pragma unroll
                for (int qf = 0; qf < 4; ++qf)
                    accv[cf][qf] = __builtin_amdgcn_mfma_f32_16x16x32_bf16(va[cf][ks], pb[qf], accv[cf][qf], 0, 0, 0);
        }
    };

    for (int jt = 0; jt < NTILES; ++jt) {
        const int buf = jt & 1;
        if (qkw) {
            // ---- S = Q K^T (16 q x 128 j), K already in registers
            f32x4 s[8];
            #pragma unroll
            for (int jf = 0; jf < 8; ++jf)
                s[jf] = __builtin_amdgcn_mfma_f32_16x16x32_bf16(qa, kb[jf], (f32x4){0.f, 0.f, 0.f, 0.f}, 0, 0, 0);

            // ---- prefetch next K tile (lands under softmax)
            const int jn = ((jt + 1) & (NTILES - 1)) * KVB;
            #pragma unroll
            for (int jf = 0; jf < 8; ++jf)
                kb[jf] = *(const bf16x8*)(ktb + (size_t)(jn + jf * 16 + c16) * DQK + g * 8);

            // ---- online softmax (rows r: q-local = 16*wid + 4g + r)
            float alpha[4];
            #pragma unroll
            for (int r = 0; r < 4; ++r) {
                float tm = s[0][r];
                #pragma unroll
                for (int jf = 1; jf < 8; ++jf) tm = fmaxf(tm, s[jf][r]);
                #pragma unroll
                for (int off = 8; off; off >>= 1) tm = fmaxf(tm, __shfl_xor(tm, off));
                const float mn = fmaxf(m[r], tm);
                alpha[r] = __expf(m[r] - mn);
                float ls = 0.f;
                #pragma unroll
                for (int jf = 0; jf < 8; ++jf) {
                    const float p = __expf(s[jf][r] - mn);
                    s[jf][r] = p;
                    ls += p;
                }
                #pragma unroll
                for (int off = 8; off; off >>= 1) ls += __shfl_xor(ls, off);
                l[r] = l[r] * alpha[r] + ls;
                m[r] = mn;
            }

            const int qbase = wid * 16 + g * 4;
            if (c16 == 0) {
                #pragma unroll
                for (int r = 0; r < 4; ++r) alpha_s[buf][qbase + r] = alpha[r];
            }
            #pragma unroll
            for (int r = 0; r < 4; ++r) {
                const int row = qbase + r;
                const int swz = (row & 15) << 3;
                #pragma unroll
                for (int jf = 0; jf < 8; ++jf)
                    P_s[buf][(row * KVB + c16 + jf * 16) ^ swz] = f2bf(s[jf][r]);
            }
        } else if (jt > 0) {
            pv_tile(jt - 1, buf ^ 1);
        }
        __syncthreads();
    }

    // final PV tile
    if (!qkw) pv_tile(NTILES - 1, (NTILES - 1) & 1);

    // ---- epilogue
    if (qkw && c16 == 0) {
        #pragma unroll
        for (int r = 0; r < 4; ++r) l_s[wid * 16 + g * 4 + r] = l[r];
    }
    __syncthreads();

    if (!qkw) {
        const float gam = gamma_p[0];
        #pragma unroll
        for (int qf = 0; qf < 4; ++qf) {
            const float linv = 1.0f / l_s[c16 + 16 * qf];
            const int   qcol = i0 + c16 + 16 * qf;
            #pragma unroll
            for (int cf = 0; cf < 4; ++cf) {
                #pragma unroll
                for (int r = 0; r < 4; ++r) {
                    const int    c = (wid & 3) * 64 + cf * 16 + g * 4 + r;
                    const size_t o = ((size_t)b * CC + c) * NN + qcol;
                    out[o] = gam * (accv[cf][qf][r] * linv) + x[o];
                }
            }
        }
    }
}

// ---------------------------------------------------------------------------
extern "C" void kernel_launch(void* const* d_in, const int* in_sizes, int n_in,
                              void* d_out, int out_size, void* d_ws, size_t ws_size,
                              hipStream_t stream)
{
    const float* x     = (const float*)d_in[0];
    const float* Wq    = (const float*)d_in[1];
    const float* bq    = (const float*)d_in[2];
    const float* Wk    = (const float*)d_in[3];
    const float* bk    = (const float*)d_in[4];
    const float* Wv    = (const float*)d_in[5];
    const float* bv    = (const float*)d_in[6];
    const float* gamma = (const float*)d_in[7];
    float* out = (float*)d_out;

    // workspace (bf16): Qt 1MB | Kt 1MB | V 8MB | xbf 8MB | Wb 160KB | biasb
    u16* qt   = (u16*)d_ws;
    u16* kt   = qt + (size_t)BB * NN * DQK;
    u16* v    = kt + (size_t)BB * NN * DQK;
    u16* xbf  = v + (size_t)BB * CC * NN;
    u16* Wb   = xbf + (size_t)BB * NN * CC;
    float* biasb = (float*)(Wb + 320 * CC);

    wprep_kernel<<<dim3(320), 256, 0, stream>>>(Wq, bq, Wk, bk, Wv, bv, Wb, biasb);
    xpose_kernel<<<dim3(NN / 64, CC / 64, BB), 256, 0, stream>>>(x, xbf);
    qkv_gemm<<<dim3(NN / 64, BB), 512, 0, stream>>>(Wb, biasb, xbf, qt, kt, v);
    attn_kernel<<<dim3(BB * (NN / QBLK)), 512, 0, stream>>>(qt, kt, v, x, gamma, out);
}